// Round 10
// baseline (240.290 us; speedup 1.0000x reference)
//
#include <hip/hip_runtime.h>
#include <hip/hip_bf16.h>

typedef __bf16 bf16x8 __attribute__((ext_vector_type(8)));
typedef __bf16 bf16x4 __attribute__((ext_vector_type(4)));
typedef float f32x4 __attribute__((ext_vector_type(4)));

#define MFMA16(a, b, c) __builtin_amdgcn_mfma_f32_16x16x32_bf16(a, b, c, 0, 0, 0)

// ---------------- problem constants ----------------
#define BATCH 4
#define SEQ   2048
#define EMB   1024
#define NHEAD 16
#define HDIM  64
#define ROWS  (BATCH * SEQ)          // 8192
#define N_QKV (3 * EMB)              // 3072
#define BH_STRIDE (SEQ * HDIM)       // 131072 elements per (b,h)

// async global->LDS, 16B per lane; lds base must be wave-uniform.
__device__ __forceinline__ void gload_lds16(const __bf16* gp, __bf16* lp) {
  __builtin_amdgcn_global_load_lds(
      (const __attribute__((address_space(1))) void*)gp,
      (__attribute__((address_space(3))) void*)lp, 16, 0, 0);
}

// ---------------- fused prep: cast x + transpose W_attn + transpose W_proj
__global__ void prep_fused(const float* __restrict__ x,
                           const float* __restrict__ W_attn,
                           const float* __restrict__ W_proj,
                           __bf16* __restrict__ xb,
                           __bf16* __restrict__ Wa_t,
                           __bf16* __restrict__ Wp_t) {
  __shared__ float tt[32][33];
  int bid = blockIdx.x, tid = threadIdx.x;
  if (bid < 8192) {
    int i = bid * 256 + tid;              // n4 = ROWS*EMB/4 = 2097152
    float4 f = ((const float4*)x)[i];
    bf16x4 o;
    o.x = (__bf16)f.x; o.y = (__bf16)f.y; o.z = (__bf16)f.z; o.w = (__bf16)f.w;
    ((bf16x4*)xb)[i] = o;
    return;
  }
  const float* src; __bf16* dst; int R, C, bx, by;
  if (bid < 8192 + 3072) {
    int t = bid - 8192;
    src = W_attn; dst = Wa_t; R = EMB; C = N_QKV;
    bx = t % 96; by = t / 96;
  } else {
    int t = bid - 11264;
    src = W_proj; dst = Wp_t; R = EMB; C = EMB;
    bx = t & 31; by = t >> 5;
  }
  int c0 = bx * 32, r0 = by * 32;
  int tx = tid & 31, ty = tid >> 5;       // 32x8
#pragma unroll
  for (int i = 0; i < 32; i += 8)
    tt[ty + i][tx] = src[(size_t)(r0 + ty + i) * C + c0 + tx];
  __syncthreads();
#pragma unroll
  for (int i = 0; i < 32; i += 8)
    dst[(size_t)(c0 + ty + i) * R + r0 + tx] = (__bf16)tt[tx][ty + i];
}

// ---------------- QKV GEMM: r4 body VERBATIM (best measured, 69.2us) -----
// r9 post-mortem: cooperative launch not graph-capturable (output never
// written). r5-r8 qkv variants (launch_bounds cap, 64KB dbuf, persistent,
// BK=32 dbuf) all lost to this r4 body: BK=64 single-buf, 32KB LDS, grid
// 1536, T2 swizzle (linear LDS dest + inverse-swizzled global source col +
// swizzled ds_read; phys colgroup = virt colgroup ^ (row&7)).
// V layout: k-slot sigma(8*qa+j) = 16*(j>>2) + 4*qa + (j&3) so attn's PV
// B-operand frag is exactly the P registers (no LDS P round-trip).
__global__ __launch_bounds__(256) void gemm_qkv(
    const __bf16* __restrict__ A, const __bf16* __restrict__ Bt,
    const float* __restrict__ bias,
    __bf16* __restrict__ Qt, __bf16* __restrict__ Kt, __bf16* __restrict__ Vt) {
  const int K = EMB;
  __shared__ __align__(16) __bf16 sA[128 * 64];
  __shared__ __align__(16) __bf16 sB[128 * 64];
  int id = blockIdx.x;
  int xcd = id & 7, j5 = id >> 3;      // j5: 0..191
  int by = j5 >> 3;                    // m-tile 0..23 (3072)
  int bx = xcd * 8 + (j5 & 7);         // n-tile 0..63 (8192)
  int m0 = by * 128, n0 = bx * 128;
  int tid = threadIdx.x;
  int wave = tid >> 6, lane = tid & 63;
  int wr = wave >> 1, wc = wave & 1;
  int l16 = lane & 15, quad = lane >> 4, quad4 = quad * 4;
  int l7 = l16 & 7;
  int srow = tid >> 3;
  int scol = ((tid & 7) ^ (srow & 7)) * 8;
  f32x4 acc[4][4] = {};
  for (int k0 = 0; k0 < K; k0 += 64) {
#pragma unroll
    for (int q = 0; q < 4; q++)
      gload_lds16(A + (size_t)(m0 + q * 32 + srow) * K + k0 + scol,
                  &sA[q * 2048 + wave * 512]);
#pragma unroll
    for (int q = 0; q < 4; q++)
      gload_lds16(Bt + (size_t)(n0 + q * 32 + srow) * K + k0 + scol,
                  &sB[q * 2048 + wave * 512]);
    __syncthreads();
#pragma unroll
    for (int kk = 0; kk < 2; kk++) {
      bf16x8 a[4], b[4];
#pragma unroll
      for (int i = 0; i < 4; i++)
        a[i] = *(const bf16x8*)(sA + (wr * 64 + i * 16 + l16) * 64 +
                                (((kk * 4 + quad) ^ l7) * 8));
#pragma unroll
      for (int j = 0; j < 4; j++)
        b[j] = *(const bf16x8*)(sB + (wc * 64 + j * 16 + l16) * 64 +
                                (((kk * 4 + quad) ^ l7) * 8));
#pragma unroll
      for (int i = 0; i < 4; i++)
#pragma unroll
        for (int j = 0; j < 4; j++) acc[i][j] = MFMA16(a[i], b[j], acc[i][j]);
    }
    __syncthreads();
  }
  const float KSC = 0.18033688011112043f;  // (1/sqrt(64)) * log2(e)
  int sec = m0 >> 10;  // wave-uniform: 0=Q 1=K 2=V
#pragma unroll
  for (int i = 0; i < 4; i++) {
    int e0 = m0 + wr * 64 + i * 16 + quad4;   // e for r=0 (r along d)
    float4 bv4 = *(const float4*)(bias + e0);
    int h = (e0 & 1023) >> 6, d0 = e0 & 63;
#pragma unroll
    for (int j = 0; j < 4; j++) {
      int scolv = n0 + wc * 64 + j * 16 + l16;
      int bidx = scolv >> 11, s = scolv & 2047;
      size_t base = (size_t)(bidx * NHEAD + h) * BH_STRIDE;
      float v0 = acc[i][j][0] + bv4.x;
      float v1 = acc[i][j][1] + bv4.y;
      float v2 = acc[i][j][2] + bv4.z;
      float v3 = acc[i][j][3] + bv4.w;
      if (sec == 0) {
        int idx = (s >> 4) * 1024 + (d0 >> 5) * 512 + ((d0 >> 3) & 3) * 128 +
                  (s & 15) * 8 + (d0 & 7);
        bf16x4 o4;
        o4.x = (__bf16)(v0 * KSC); o4.y = (__bf16)(v1 * KSC);
        o4.z = (__bf16)(v2 * KSC); o4.w = (__bf16)(v3 * KSC);
        *(bf16x4*)(Qt + base + idx) = o4;
      } else if (sec == 1) {
        int idx = (s >> 6) * 4096 + ((s >> 4) & 3) * 1024 + (d0 >> 5) * 512 +
                  ((d0 >> 3) & 3) * 128 + (s & 15) * 8 + (d0 & 7);
        bf16x4 o4;
        o4.x = (__bf16)v0; o4.y = (__bf16)v1;
        o4.z = (__bf16)v2; o4.w = (__bf16)v3;
        *(bf16x4*)(Kt + base + idx) = o4;
      } else {
        // V: A-frag slot for d=row, kv=s, with sigma k-slot mapping.
        int idx = (s >> 6) * 4096 + (d0 >> 4) * 1024 + ((s >> 5) & 1) * 512 +
                  ((s >> 2) & 3) * 128 + ((s >> 4) & 1) * 4 + (s & 3) +
                  quad4 * 8;
        Vt[base + idx] = (__bf16)v0;
        Vt[base + idx + 8] = (__bf16)v1;
        Vt[base + idx + 16] = (__bf16)v2;
        Vt[base + idx + 24] = (__bf16)v3;
      }
    }
  }
}

// ---------------- flash attention: 256-row q-blocks, 8 waves -------------
// Change vs r8: q-block 128 -> 256 rows (8 waves, 512 threads, 512 blocks).
// Each K/V tile staged once per 256 q-rows instead of per 128: block-tile
// iterations 17408 -> 9216 (MFMA identical), halving staging traffic and
// per-iter fixed costs. All 512 blocks co-resident (2/CU, 64KB LDS) -> no
// refill churn; heavy blocks (qb'=7, 32 tiles) start at t=0 (heavy-first).
// Per-wave body unchanged: P-in-register (V sigma k-slot layout), dbuf K/V,
// one barrier per tile, wave-uniform masked-tile skip, setprio.
__global__ __launch_bounds__(512) void attn_fwd(
    const __bf16* __restrict__ Qt, const __bf16* __restrict__ Kt,
    const __bf16* __restrict__ Vt, __bf16* __restrict__ Y) {
  __shared__ __align__(16) __bf16 sK[2][4096];       // 2x8 KB K tiles
  __shared__ __align__(16) __bf16 sV[2][4096];       // 2x8 KB V tiles
  int id = blockIdx.x;                   // 512 blocks
  int qb = 7 - (id >> 6);                // heavy blocks dispatched first
  int hb = id & 63;
  int h = hb >> 2, b = hb & 3;
  int tid = threadIdx.x;                 // 0..511
  int wave = tid >> 6, lane = tid & 63;  // 8 waves x 32 q rows
  int l16 = lane & 15, quad = lane >> 4, quad4 = quad * 4;
  int q0 = qb * 256;
  size_t bh = (size_t)b * NHEAD + h;
  const __bf16* Qh = Qt + bh * BH_STRIDE;
  const __bf16* Kh = Kt + bh * BH_STRIDE;
  const __bf16* Vh = Vt + bh * BH_STRIDE;
  int mq = q0 + wave * 32;               // wave covers q rows mq..mq+31
  const __bf16* qbase = Qh + (size_t)(mq >> 4) * 1024 + lane * 8;
  bf16x8 qa0 = *(const bf16x8*)(qbase);          // q rows mq..mq+15
  bf16x8 qa1 = *(const bf16x8*)(qbase + 512);
  bf16x8 qb0 = *(const bf16x8*)(qbase + 1024);   // q rows mq+16..mq+31
  bf16x8 qb1 = *(const bf16x8*)(qbase + 1536);
  f32x4 accA[4] = {}, accB[4] = {};
  float lA = 0.f, lB = 0.f;
  const float NEG_INF = -__builtin_inff();
  int nt = (q0 + 256) >> 6;              // kv tiles: 4*(qb+1)
  // prologue: stage tile 0 into buffer 0 (512 thr x 16B = 8KB each)
  gload_lds16(Kh + tid * 8, sK[0] + tid * 8);
  gload_lds16(Vh + tid * 8, sV[0] + tid * 8);
  __syncthreads();
  int cur = 0;
  for (int it = 0; it < nt; ++it) {
    int kt = it * 64;
    // prefetch tile it+1 into the other buffer (completes during compute;
    // drained by the end-of-tile barrier's vmcnt(0))
    if (it + 1 < nt) {
      gload_lds16(Kh + (size_t)(it + 1) * 4096 + tid * 8, sK[cur ^ 1] + tid * 8);
      gload_lds16(Vh + (size_t)(it + 1) * 4096 + tid * 8, sV[cur ^ 1] + tid * 8);
    }
    if (kt <= mq + 31) {                 // wave-uniform: skip fully-masked
      const __bf16* sKc = sK[cur];
      const __bf16* sVc = sV[cur];
      bool diag = (kt + 64 > mq);        // wave-uniform
      int relA = mq + l16 - kt;          // keep k_local <= relA (frag A)
      int relB = relA + 16;
      bf16x8 PA0, PA1, PB0, PB1;         // P frags, sigma k-slot order
      __builtin_amdgcn_s_setprio(1);
#pragma unroll
      for (int t = 0; t < 4; t++) {
        bf16x8 ka = *(const bf16x8*)(sKc + t * 1024 + lane * 8);
        bf16x8 kb = *(const bf16x8*)(sKc + t * 1024 + 512 + lane * 8);
        f32x4 zA = {}, zB = {};
        zA = MFMA16(ka, qa0, zA);
        zA = MFMA16(kb, qa1, zA);
        zB = MFMA16(ka, qb0, zB);
        zB = MFMA16(kb, qb1, zB);
        int kl = t * 16 + quad4;
        float pA[4], pB[4];
        if (diag) {
#pragma unroll
          for (int r = 0; r < 4; r++) {
            pA[r] = __builtin_amdgcn_exp2f(kl + r > relA ? NEG_INF : zA[r]);
            pB[r] = __builtin_amdgcn_exp2f(kl + r > relB ? NEG_INF : zB[r]);
          }
        } else {
#pragma unroll
          for (int r = 0; r < 4; r++) {
            pA[r] = __builtin_amdgcn_exp2f(zA[r]);
            pB[r] = __builtin_amdgcn_exp2f(zB[r]);
          }
        }
        lA += (pA[0] + pA[1]) + (pA[2] + pA[3]);
        lB += (pB[0] + pB[1]) + (pB[2] + pB[3]);
        // pack: tile t -> chunk t>>1, slots 4*(t&1)+r  (all compile-time)
        if (t == 0) {
          PA0[0] = (__bf16)pA[0]; PA0[1] = (__bf16)pA[1];
          PA0[2] = (__bf16)pA[2]; PA0[3] = (__bf16)pA[3];
          PB0[0] = (__bf16)pB[0]; PB0[1] = (__bf16)pB[1];
          PB0[2] = (__bf16)pB[2]; PB0[3] = (__bf16)pB[3];
        } else if (t == 1) {
          PA0[4] = (__bf16)pA[0]; PA0[5] = (__bf16)pA[1];
          PA0[6] = (__bf16)pA[2]; PA0[7] = (__bf16)pA[3];
          PB0[4] = (__bf16)pB[0]; PB0[5] = (__bf16)pB[1];
          PB0[6] = (__bf16)pB[2]; PB0[7] = (__bf16)pB[3];
        } else if (t == 2) {
          PA1[0] = (__bf16)pA[0]; PA1[1] = (__bf16)pA[1];
          PA1[2] = (__bf16)pA[2]; PA1[3] = (__bf16)pA[3];
          PB1[0] = (__bf16)pB[0]; PB1[1] = (__bf16)pB[1];
          PB1[2] = (__bf16)pB[2]; PB1[3] = (__bf16)pB[3];
        } else {
          PA1[4] = (__bf16)pA[0]; PA1[5] = (__bf16)pA[1];
          PA1[6] = (__bf16)pA[2]; PA1[7] = (__bf16)pA[3];
          PB1[4] = (__bf16)pB[0]; PB1[5] = (__bf16)pB[1];
          PB1[6] = (__bf16)pB[2]; PB1[7] = (__bf16)pB[3];
        }
      }
      // PV: V frags in sigma order; P frags are lane-local registers
#pragma unroll
      for (int jj = 0; jj < 4; jj++) {
        bf16x8 va = *(const bf16x8*)(sVc + jj * 1024 + lane * 8);
        bf16x8 vb = *(const bf16x8*)(sVc + jj * 1024 + 512 + lane * 8);
        accA[jj] = MFMA16(va, PA0, accA[jj]);
        accA[jj] = MFMA16(vb, PA1, accA[jj]);
        accB[jj] = MFMA16(va, PB0, accB[jj]);
        accB[jj] = MFMA16(vb, PB1, accB[jj]);
      }
      __builtin_amdgcn_s_setprio(0);
    }
    __syncthreads();   // drains prefetch (vmcnt 0) + all waves done with cur
    cur ^= 1;
  }
  // epilogue: cross-quad l reduce, O^T[d][q] -> Y
  lA += __shfl_xor(lA, 16); lA += __shfl_xor(lA, 32);
  lB += __shfl_xor(lB, 16); lB += __shfl_xor(lB, 32);
  float invA = 1.f / lA, invB = 1.f / lB;
  int gqA = mq + l16, gqB = mq + 16 + l16;
#pragma unroll
  for (int jj = 0; jj < 4; jj++) {
    bf16x4 oA, oB;
    oA.x = (__bf16)(accA[jj][0] * invA);
    oA.y = (__bf16)(accA[jj][1] * invA);
    oA.z = (__bf16)(accA[jj][2] * invA);
    oA.w = (__bf16)(accA[jj][3] * invA);
    oB.x = (__bf16)(accB[jj][0] * invB);
    oB.y = (__bf16)(accB[jj][1] * invB);
    oB.z = (__bf16)(accB[jj][2] * invB);
    oB.w = (__bf16)(accB[jj][3] * invB);
    *(bf16x4*)(Y + ((size_t)b * SEQ + gqA) * EMB + h * HDIM + jj * 16 + quad4) = oA;
    *(bf16x4*)(Y + ((size_t)b * SEQ + gqB) * EMB + h * HDIM + jj * 16 + quad4) = oB;
  }
}

// ---------------- proj GEMM (BK=64 + T2 swizzle + XCD swizzle) ----------
__global__ __launch_bounds__(256) void gemm_proj(
    const __bf16* __restrict__ A, const __bf16* __restrict__ Bt,
    const float* __restrict__ bias, float* __restrict__ out) {
  const int K = EMB;
  __shared__ __align__(16) __bf16 sA[128 * 64];
  __shared__ __align__(16) __bf16 sB[128 * 64];
  int id = blockIdx.x;
  int lid = (id & 7) * (512 >> 3) + (id >> 3);
  int bx = lid & 7, by = lid >> 3;
  int m0 = by * 128, n0 = bx * 128;
  int tid = threadIdx.x;
  int wave = tid >> 6, lane = tid & 63;
  int wr = wave >> 1, wc = wave & 1;
  int l16 = lane & 15, quad = lane >> 4;
  int l7 = l16 & 7;
  int srow = tid >> 3;
  int scol = ((tid & 7) ^ (srow & 7)) * 8;
  f32x4 acc[4][4] = {};
  for (int k0 = 0; k0 < K; k0 += 64) {
#pragma unroll
    for (int q = 0; q < 4; q++)
      gload_lds16(A + (size_t)(m0 + q * 32 + srow) * K + k0 + scol,
                  &sA[q * 2048 + wave * 512]);
#pragma unroll
    for (int q = 0; q < 4; q++)
      gload_lds16(Bt + (size_t)(n0 + q * 32 + srow) * K + k0 + scol,
                  &sB[q * 2048 + wave * 512]);
    __syncthreads();
#pragma unroll
    for (int kk = 0; kk < 2; kk++) {
      bf16x8 a[4], b[4];
#pragma unroll
      for (int i = 0; i < 4; i++)
        a[i] = *(const bf16x8*)(sA + (wr * 64 + i * 16 + l16) * 64 +
                                (((kk * 4 + quad) ^ l7) * 8));
#pragma unroll
      for (int j = 0; j < 4; j++)
        b[j] = *(const bf16x8*)(sB + (wc * 64 + j * 16 + l16) * 64 +
                                (((kk * 4 + quad) ^ l7) * 8));
#pragma unroll
      for (int i = 0; i < 4; i++)
#pragma unroll
        for (int j = 0; j < 4; j++) acc[i][j] = MFMA16(a[i], b[j], acc[i][j]);
    }
    __syncthreads();
  }
#pragma unroll
  for (int i = 0; i < 4; i++) {
    int row = m0 + wr * 64 + i * 16 + quad * 4;
#pragma unroll
    for (int j = 0; j < 4; j++) {
      int col = n0 + wc * 64 + j * 16 + l16;
      float bv = bias[col];
#pragma unroll
      for (int r = 0; r < 4; r++)
        out[(size_t)(row + r) * EMB + col] = acc[i][j][r] + bv;
    }
  }
}

// ---------------- launch ----------------
extern "C" void kernel_launch(void* const* d_in, const int* in_sizes, int n_in,
                              void* d_out, int out_size, void* d_ws, size_t ws_size,
                              hipStream_t stream) {
  const float* x      = (const float*)d_in[0];
  const float* W_attn = (const float*)d_in[1];
  const float* b_attn = (const float*)d_in[2];
  const float* W_proj = (const float*)d_in[3];
  const float* b_proj = (const float*)d_in[4];
  float* out = (float*)d_out;

  char* ws = (char*)d_ws;
  size_t off = 0;
  __bf16* xb   = (__bf16*)(ws + off); off += (size_t)ROWS * EMB * 2;
  __bf16* Wa_t = (__bf16*)(ws + off); off += (size_t)N_QKV * EMB * 2;
  __bf16* Wp_t = (__bf16*)(ws + off); off += (size_t)EMB * EMB * 2;
  __bf16* Qt   = (__bf16*)(ws + off); off += (size_t)ROWS * EMB * 2;
  __bf16* Kt   = (__bf16*)(ws + off); off += (size_t)ROWS * EMB * 2;
  __bf16* Vt   = (__bf16*)(ws + off); off += (size_t)ROWS * EMB * 2;
  __bf16* Yb   = (__bf16*)(ws + off); off += (size_t)ROWS * EMB * 2;

  prep_fused<<<dim3(12288), 256, 0, stream>>>(x, W_attn, W_proj, xb, Wa_t, Wp_t);
  // qkv: r4 config — BK=64 single-buf, 1536 blocks
  gemm_qkv<<<dim3(1536), 256, 0, stream>>>(Wa_t, xb, b_attn, Qt, Kt, Vt);
  // attn: 256-row q-blocks, 8 waves, 512 blocks (all co-resident)
  attn_fwd<<<dim3((SEQ / 256) * NHEAD * BATCH), 512, 0, stream>>>(Qt, Kt, Vt, Yb);
  gemm_proj<<<dim3(512), 256, 0, stream>>>(Yb, Wp_t, b_proj, out);
}

// Round 11
// 230.070 us; speedup vs baseline: 1.0444x; 1.0444x over previous
//
#include <hip/hip_runtime.h>
#include <hip/hip_bf16.h>

typedef __bf16 bf16x8 __attribute__((ext_vector_type(8)));
typedef __bf16 bf16x4 __attribute__((ext_vector_type(4)));
typedef float f32x4 __attribute__((ext_vector_type(4)));

#define MFMA16(a, b, c) __builtin_amdgcn_mfma_f32_16x16x32_bf16(a, b, c, 0, 0, 0)

// ---------------- problem constants ----------------
#define BATCH 4
#define SEQ   2048
#define EMB   1024
#define NHEAD 16
#define HDIM  64
#define ROWS  (BATCH * SEQ)          // 8192
#define N_QKV (3 * EMB)              // 3072
#define BH_STRIDE (SEQ * HDIM)       // 131072 elements per (b,h)

// async global->LDS, 16B per lane; lds base must be wave-uniform.
__device__ __forceinline__ void gload_lds16(const __bf16* gp, __bf16* lp) {
  __builtin_amdgcn_global_load_lds(
      (const __attribute__((address_space(1))) void*)gp,
      (__attribute__((address_space(3))) void*)lp, 16, 0, 0);
}

// ---------------- fused prep: cast x + transpose W_attn + transpose W_proj
__global__ void prep_fused(const float* __restrict__ x,
                           const float* __restrict__ W_attn,
                           const float* __restrict__ W_proj,
                           __bf16* __restrict__ xb,
                           __bf16* __restrict__ Wa_t,
                           __bf16* __restrict__ Wp_t) {
  __shared__ float tt[32][33];
  int bid = blockIdx.x, tid = threadIdx.x;
  if (bid < 8192) {
    int i = bid * 256 + tid;              // n4 = ROWS*EMB/4 = 2097152
    float4 f = ((const float4*)x)[i];
    bf16x4 o;
    o.x = (__bf16)f.x; o.y = (__bf16)f.y; o.z = (__bf16)f.z; o.w = (__bf16)f.w;
    ((bf16x4*)xb)[i] = o;
    return;
  }
  const float* src; __bf16* dst; int R, C, bx, by;
  if (bid < 8192 + 3072) {
    int t = bid - 8192;
    src = W_attn; dst = Wa_t; R = EMB; C = N_QKV;
    bx = t % 96; by = t / 96;
  } else {
    int t = bid - 11264;
    src = W_proj; dst = Wp_t; R = EMB; C = EMB;
    bx = t & 31; by = t >> 5;
  }
  int c0 = bx * 32, r0 = by * 32;
  int tx = tid & 31, ty = tid >> 5;       // 32x8
#pragma unroll
  for (int i = 0; i < 32; i += 8)
    tt[ty + i][tx] = src[(size_t)(r0 + ty + i) * C + c0 + tx];
  __syncthreads();
#pragma unroll
  for (int i = 0; i < 32; i += 8)
    dst[(size_t)(c0 + ty + i) * R + r0 + tx] = (__bf16)tt[tx][ty + i];
}

// ---------------- QKV GEMM: r4 body + hoisted staging pointers -----------
// r10 reconfirmed the r4 structure at 69.0us (best of 6 variants). Change
// here: strength-reduce staging addresses. VALUBusy 43% > MfmaUtil 31%, and
// the per-K-iter (row)*K+k0 64-bit recomputation (~8 mul-adds/iter/thread,
// m98-style v_lshl_add_u64) is the top non-MFMA VALU consumer. Hoist base
// pointers, advance by 64 per iter; q-offsets become compile-time consts.
// T2 swizzle (rule 21): linear LDS dest + inverse-swizzled global source col
// + swizzled ds_read; phys colgroup = virt colgroup ^ (row&7).
// V layout: k-slot sigma(8*qa+j) = 16*(j>>2) + 4*qa + (j&3) so attn's PV
// B-operand frag is exactly the P registers (no LDS P round-trip).
__global__ __launch_bounds__(256) void gemm_qkv(
    const __bf16* __restrict__ A, const __bf16* __restrict__ Bt,
    const float* __restrict__ bias,
    __bf16* __restrict__ Qt, __bf16* __restrict__ Kt, __bf16* __restrict__ Vt) {
  const int K = EMB;
  __shared__ __align__(16) __bf16 sA[128 * 64];
  __shared__ __align__(16) __bf16 sB[128 * 64];
  int id = blockIdx.x;
  int xcd = id & 7, j5 = id >> 3;      // j5: 0..191
  int by = j5 >> 3;                    // m-tile 0..23 (3072)
  int bx = xcd * 8 + (j5 & 7);         // n-tile 0..63 (8192)
  int m0 = by * 128, n0 = bx * 128;
  int tid = threadIdx.x;
  int wave = tid >> 6, lane = tid & 63;
  int wr = wave >> 1, wc = wave & 1;
  int l16 = lane & 15, quad = lane >> 4, quad4 = quad * 4;
  int l7 = l16 & 7;
  int srow = tid >> 3;
  int scol = ((tid & 7) ^ (srow & 7)) * 8;
  // hoisted staging pointers (advance by 64 per K-iter; q-offsets constant)
  const __bf16* pa = A + (size_t)(m0 + srow) * K + scol;
  const __bf16* pb = Bt + (size_t)(n0 + srow) * K + scol;
  f32x4 acc[4][4] = {};
  for (int k0 = 0; k0 < K; k0 += 64) {
#pragma unroll
    for (int q = 0; q < 4; q++)
      gload_lds16(pa + (size_t)q * 32 * EMB, &sA[q * 2048 + wave * 512]);
#pragma unroll
    for (int q = 0; q < 4; q++)
      gload_lds16(pb + (size_t)q * 32 * EMB, &sB[q * 2048 + wave * 512]);
    __syncthreads();
#pragma unroll
    for (int kk = 0; kk < 2; kk++) {
      bf16x8 a[4], b[4];
#pragma unroll
      for (int i = 0; i < 4; i++)
        a[i] = *(const bf16x8*)(sA + (wr * 64 + i * 16 + l16) * 64 +
                                (((kk * 4 + quad) ^ l7) * 8));
#pragma unroll
      for (int j = 0; j < 4; j++)
        b[j] = *(const bf16x8*)(sB + (wc * 64 + j * 16 + l16) * 64 +
                                (((kk * 4 + quad) ^ l7) * 8));
#pragma unroll
      for (int i = 0; i < 4; i++)
#pragma unroll
        for (int j = 0; j < 4; j++) acc[i][j] = MFMA16(a[i], b[j], acc[i][j]);
    }
    __syncthreads();
    pa += 64;
    pb += 64;
  }
  const float KSC = 0.18033688011112043f;  // (1/sqrt(64)) * log2(e)
  int sec = m0 >> 10;  // wave-uniform: 0=Q 1=K 2=V
#pragma unroll
  for (int i = 0; i < 4; i++) {
    int e0 = m0 + wr * 64 + i * 16 + quad4;   // e for r=0 (r along d)
    float4 bv4 = *(const float4*)(bias + e0);
    int h = (e0 & 1023) >> 6, d0 = e0 & 63;
#pragma unroll
    for (int j = 0; j < 4; j++) {
      int scolv = n0 + wc * 64 + j * 16 + l16;
      int bidx = scolv >> 11, s = scolv & 2047;
      size_t base = (size_t)(bidx * NHEAD + h) * BH_STRIDE;
      float v0 = acc[i][j][0] + bv4.x;
      float v1 = acc[i][j][1] + bv4.y;
      float v2 = acc[i][j][2] + bv4.z;
      float v3 = acc[i][j][3] + bv4.w;
      if (sec == 0) {
        int idx = (s >> 4) * 1024 + (d0 >> 5) * 512 + ((d0 >> 3) & 3) * 128 +
                  (s & 15) * 8 + (d0 & 7);
        bf16x4 o4;
        o4.x = (__bf16)(v0 * KSC); o4.y = (__bf16)(v1 * KSC);
        o4.z = (__bf16)(v2 * KSC); o4.w = (__bf16)(v3 * KSC);
        *(bf16x4*)(Qt + base + idx) = o4;
      } else if (sec == 1) {
        int idx = (s >> 6) * 4096 + ((s >> 4) & 3) * 1024 + (d0 >> 5) * 512 +
                  ((d0 >> 3) & 3) * 128 + (s & 15) * 8 + (d0 & 7);
        bf16x4 o4;
        o4.x = (__bf16)v0; o4.y = (__bf16)v1;
        o4.z = (__bf16)v2; o4.w = (__bf16)v3;
        *(bf16x4*)(Kt + base + idx) = o4;
      } else {
        // V: A-frag slot for d=row, kv=s, with sigma k-slot mapping.
        int idx = (s >> 6) * 4096 + (d0 >> 4) * 1024 + ((s >> 5) & 1) * 512 +
                  ((s >> 2) & 3) * 128 + ((s >> 4) & 1) * 4 + (s & 3) +
                  quad4 * 8;
        Vt[base + idx] = (__bf16)v0;
        Vt[base + idx + 8] = (__bf16)v1;
        Vt[base + idx + 16] = (__bf16)v2;
        Vt[base + idx + 24] = (__bf16)v3;
      }
    }
  }
}

// ---------------- flash attention: r4 128-row version VERBATIM -----------
// r10 post-mortem: 256-row/8-wave regressed ~10us at the SAME 16 waves/CU —
// the 8-wave barrier convoy + halved per-CU independent barrier groups cost
// more than halved staging saved. 128-row/4-wave/1024-block is the measured
// best. P-in-register (V sigma k-slot layout), dbuf K/V, one barrier per
// tile, wave-uniform masked-tile skip, setprio, heavy-first order.
__global__ __launch_bounds__(256, 4) void attn_fwd(
    const __bf16* __restrict__ Qt, const __bf16* __restrict__ Kt,
    const __bf16* __restrict__ Vt, __bf16* __restrict__ Y) {
  __shared__ __align__(16) __bf16 sK[2][4096];       // 2x8 KB K tiles
  __shared__ __align__(16) __bf16 sV[2][4096];       // 2x8 KB V tiles
  int id = blockIdx.x;
  int g = id >> 6;                       // 0..15
  int qb = 15 - g;                       // heavy blocks dispatched first
  int hb = id & 63;
  int h = hb >> 2, b = hb & 3;
  int tid = threadIdx.x;
  int wave = tid >> 6, lane = tid & 63;
  int l16 = lane & 15, quad = lane >> 4, quad4 = quad * 4;
  int q0 = qb * 128;
  size_t bh = (size_t)b * NHEAD + h;
  const __bf16* Qh = Qt + bh * BH_STRIDE;
  const __bf16* Kh = Kt + bh * BH_STRIDE;
  const __bf16* Vh = Vt + bh * BH_STRIDE;
  int mq = q0 + wave * 32;               // wave covers q rows mq..mq+31
  const __bf16* qbase = Qh + (size_t)(mq >> 4) * 1024 + lane * 8;
  bf16x8 qa0 = *(const bf16x8*)(qbase);          // q rows mq..mq+15
  bf16x8 qa1 = *(const bf16x8*)(qbase + 512);
  bf16x8 qb0 = *(const bf16x8*)(qbase + 1024);   // q rows mq+16..mq+31
  bf16x8 qb1 = *(const bf16x8*)(qbase + 1536);
  f32x4 accA[4] = {}, accB[4] = {};
  float lA = 0.f, lB = 0.f;
  const float NEG_INF = -__builtin_inff();
  int nt = (q0 + 128) >> 6;              // kv tiles to process
  // prologue: stage tile 0 into buffer 0
  gload_lds16(Kh + tid * 8, sK[0] + tid * 8);
  gload_lds16(Kh + 2048 + tid * 8, sK[0] + 2048 + tid * 8);
  gload_lds16(Vh + tid * 8, sV[0] + tid * 8);
  gload_lds16(Vh + 2048 + tid * 8, sV[0] + 2048 + tid * 8);
  __syncthreads();
  int cur = 0;
  for (int it = 0; it < nt; ++it) {
    int kt = it * 64;
    // prefetch tile it+1 into the other buffer (completes during compute;
    // drained by the end-of-tile barrier's vmcnt(0))
    if (it + 1 < nt) {
      const __bf16* kg = Kh + (size_t)(it + 1) * 4096 + tid * 8;
      const __bf16* vg = Vh + (size_t)(it + 1) * 4096 + tid * 8;
      __bf16* dK = sK[cur ^ 1] + tid * 8;
      __bf16* dV = sV[cur ^ 1] + tid * 8;
      gload_lds16(kg, dK);
      gload_lds16(kg + 2048, dK + 2048);
      gload_lds16(vg, dV);
      gload_lds16(vg + 2048, dV + 2048);
    }
    if (kt <= mq + 31) {                 // wave-uniform: skip fully-masked
      const __bf16* sKc = sK[cur];
      const __bf16* sVc = sV[cur];
      bool diag = (kt + 64 > mq);        // wave-uniform
      int relA = mq + l16 - kt;          // keep k_local <= relA (frag A)
      int relB = relA + 16;
      bf16x8 PA0, PA1, PB0, PB1;         // P frags, sigma k-slot order
      __builtin_amdgcn_s_setprio(1);
#pragma unroll
      for (int t = 0; t < 4; t++) {
        bf16x8 ka = *(const bf16x8*)(sKc + t * 1024 + lane * 8);
        bf16x8 kb = *(const bf16x8*)(sKc + t * 1024 + 512 + lane * 8);
        f32x4 zA = {}, zB = {};
        zA = MFMA16(ka, qa0, zA);
        zA = MFMA16(kb, qa1, zA);
        zB = MFMA16(ka, qb0, zB);
        zB = MFMA16(kb, qb1, zB);
        int kl = t * 16 + quad4;
        float pA[4], pB[4];
        if (diag) {
#pragma unroll
          for (int r = 0; r < 4; r++) {
            pA[r] = __builtin_amdgcn_exp2f(kl + r > relA ? NEG_INF : zA[r]);
            pB[r] = __builtin_amdgcn_exp2f(kl + r > relB ? NEG_INF : zB[r]);
          }
        } else {
#pragma unroll
          for (int r = 0; r < 4; r++) {
            pA[r] = __builtin_amdgcn_exp2f(zA[r]);
            pB[r] = __builtin_amdgcn_exp2f(zB[r]);
          }
        }
        lA += (pA[0] + pA[1]) + (pA[2] + pA[3]);
        lB += (pB[0] + pB[1]) + (pB[2] + pB[3]);
        // pack: tile t -> chunk t>>1, slots 4*(t&1)+r  (all compile-time)
        if (t == 0) {
          PA0[0] = (__bf16)pA[0]; PA0[1] = (__bf16)pA[1];
          PA0[2] = (__bf16)pA[2]; PA0[3] = (__bf16)pA[3];
          PB0[0] = (__bf16)pB[0]; PB0[1] = (__bf16)pB[1];
          PB0[2] = (__bf16)pB[2]; PB0[3] = (__bf16)pB[3];
        } else if (t == 1) {
          PA0[4] = (__bf16)pA[0]; PA0[5] = (__bf16)pA[1];
          PA0[6] = (__bf16)pA[2]; PA0[7] = (__bf16)pA[3];
          PB0[4] = (__bf16)pB[0]; PB0[5] = (__bf16)pB[1];
          PB0[6] = (__bf16)pB[2]; PB0[7] = (__bf16)pB[3];
        } else if (t == 2) {
          PA1[0] = (__bf16)pA[0]; PA1[1] = (__bf16)pA[1];
          PA1[2] = (__bf16)pA[2]; PA1[3] = (__bf16)pA[3];
          PB1[0] = (__bf16)pB[0]; PB1[1] = (__bf16)pB[1];
          PB1[2] = (__bf16)pB[2]; PB1[3] = (__bf16)pB[3];
        } else {
          PA1[4] = (__bf16)pA[0]; PA1[5] = (__bf16)pA[1];
          PA1[6] = (__bf16)pA[2]; PA1[7] = (__bf16)pA[3];
          PB1[4] = (__bf16)pB[0]; PB1[5] = (__bf16)pB[1];
          PB1[6] = (__bf16)pB[2]; PB1[7] = (__bf16)pB[3];
        }
      }
      // PV: V frags in sigma order; P frags are lane-local registers
#pragma unroll
      for (int jj = 0; jj < 4; jj++) {
        bf16x8 va = *(const bf16x8*)(sVc + jj * 1024 + lane * 8);
        bf16x8 vb = *(const bf16x8*)(sVc + jj * 1024 + 512 + lane * 8);
        accA[jj] = MFMA16(va, PA0, accA[jj]);
        accA[jj] = MFMA16(vb, PA1, accA[jj]);
        accB[jj] = MFMA16(va, PB0, accB[jj]);
        accB[jj] = MFMA16(vb, PB1, accB[jj]);
      }
      __builtin_amdgcn_s_setprio(0);
    }
    __syncthreads();   // drains prefetch (vmcnt 0) + all waves done with cur
    cur ^= 1;
  }
  // epilogue: cross-quad l reduce, O^T[d][q] -> Y
  lA += __shfl_xor(lA, 16); lA += __shfl_xor(lA, 32);
  lB += __shfl_xor(lB, 16); lB += __shfl_xor(lB, 32);
  float invA = 1.f / lA, invB = 1.f / lB;
  int gqA = mq + l16, gqB = mq + 16 + l16;
#pragma unroll
  for (int jj = 0; jj < 4; jj++) {
    bf16x4 oA, oB;
    oA.x = (__bf16)(accA[jj][0] * invA);
    oA.y = (__bf16)(accA[jj][1] * invA);
    oA.z = (__bf16)(accA[jj][2] * invA);
    oA.w = (__bf16)(accA[jj][3] * invA);
    oB.x = (__bf16)(accB[jj][0] * invB);
    oB.y = (__bf16)(accB[jj][1] * invB);
    oB.z = (__bf16)(accB[jj][2] * invB);
    oB.w = (__bf16)(accB[jj][3] * invB);
    *(bf16x4*)(Y + ((size_t)b * SEQ + gqA) * EMB + h * HDIM + jj * 16 + quad4) = oA;
    *(bf16x4*)(Y + ((size_t)b * SEQ + gqB) * EMB + h * HDIM + jj * 16 + quad4) = oB;
  }
}

// ---------------- proj GEMM (r4 body + hoisted staging pointers) --------
__global__ __launch_bounds__(256) void gemm_proj(
    const __bf16* __restrict__ A, const __bf16* __restrict__ Bt,
    const float* __restrict__ bias, float* __restrict__ out) {
  const int K = EMB;
  __shared__ __align__(16) __bf16 sA[128 * 64];
  __shared__ __align__(16) __bf16 sB[128 * 64];
  int id = blockIdx.x;
  int lid = (id & 7) * (512 >> 3) + (id >> 3);
  int bx = lid & 7, by = lid >> 3;
  int m0 = by * 128, n0 = bx * 128;
  int tid = threadIdx.x;
  int wave = tid >> 6, lane = tid & 63;
  int wr = wave >> 1, wc = wave & 1;
  int l16 = lane & 15, quad = lane >> 4;
  int l7 = l16 & 7;
  int srow = tid >> 3;
  int scol = ((tid & 7) ^ (srow & 7)) * 8;
  const __bf16* pa = A + (size_t)(m0 + srow) * K + scol;
  const __bf16* pb = Bt + (size_t)(n0 + srow) * K + scol;
  f32x4 acc[4][4] = {};
  for (int k0 = 0; k0 < K; k0 += 64) {
#pragma unroll
    for (int q = 0; q < 4; q++)
      gload_lds16(pa + (size_t)q * 32 * EMB, &sA[q * 2048 + wave * 512]);
#pragma unroll
    for (int q = 0; q < 4; q++)
      gload_lds16(pb + (size_t)q * 32 * EMB, &sB[q * 2048 + wave * 512]);
    __syncthreads();
#pragma unroll
    for (int kk = 0; kk < 2; kk++) {
      bf16x8 a[4], b[4];
#pragma unroll
      for (int i = 0; i < 4; i++)
        a[i] = *(const bf16x8*)(sA + (wr * 64 + i * 16 + l16) * 64 +
                                (((kk * 4 + quad) ^ l7) * 8));
#pragma unroll
      for (int j = 0; j < 4; j++)
        b[j] = *(const bf16x8*)(sB + (wc * 64 + j * 16 + l16) * 64 +
                                (((kk * 4 + quad) ^ l7) * 8));
#pragma unroll
      for (int i = 0; i < 4; i++)
#pragma unroll
        for (int j = 0; j < 4; j++) acc[i][j] = MFMA16(a[i], b[j], acc[i][j]);
    }
    __syncthreads();
    pa += 64;
    pb += 64;
  }
#pragma unroll
  for (int i = 0; i < 4; i++) {
    int row = m0 + wr * 64 + i * 16 + quad * 4;
#pragma unroll
    for (int j = 0; j < 4; j++) {
      int col = n0 + wc * 64 + j * 16 + l16;
      float bv = bias[col];
#pragma unroll
      for (int r = 0; r < 4; r++)
        out[(size_t)(row + r) * EMB + col] = acc[i][j][r] + bv;
    }
  }
}

// ---------------- launch ----------------
extern "C" void kernel_launch(void* const* d_in, const int* in_sizes, int n_in,
                              void* d_out, int out_size, void* d_ws, size_t ws_size,
                              hipStream_t stream) {
  const float* x      = (const float*)d_in[0];
  const float* W_attn = (const float*)d_in[1];
  const float* b_attn = (const float*)d_in[2];
  const float* W_proj = (const float*)d_in[3];
  const float* b_proj = (const float*)d_in[4];
  float* out = (float*)d_out;

  char* ws = (char*)d_ws;
  size_t off = 0;
  __bf16* xb   = (__bf16*)(ws + off); off += (size_t)ROWS * EMB * 2;
  __bf16* Wa_t = (__bf16*)(ws + off); off += (size_t)N_QKV * EMB * 2;
  __bf16* Wp_t = (__bf16*)(ws + off); off += (size_t)EMB * EMB * 2;
  __bf16* Qt   = (__bf16*)(ws + off); off += (size_t)ROWS * EMB * 2;
  __bf16* Kt   = (__bf16*)(ws + off); off += (size_t)ROWS * EMB * 2;
  __bf16* Vt   = (__bf16*)(ws + off); off += (size_t)ROWS * EMB * 2;
  __bf16* Yb   = (__bf16*)(ws + off); off += (size_t)ROWS * EMB * 2;

  prep_fused<<<dim3(12288), 256, 0, stream>>>(x, W_attn, W_proj, xb, Wa_t, Wp_t);
  // qkv: r4 config — BK=64 single-buf, 1536 blocks
  gemm_qkv<<<dim3(1536), 256, 0, stream>>>(Wa_t, xb, b_attn, Qt, Kt, Vt);
  // attn: r4 config — 128-row q-blocks, 4 waves, 1024 blocks
  attn_fwd<<<dim3((SEQ / 128) * NHEAD * BATCH), 256, 0, stream>>>(Qt, Kt, Vt, Yb);
  gemm_proj<<<dim3(512), 256, 0, stream>>>(Yb, Wp_t, b_proj, out);
}